// Round 1
// baseline (1364.763 us; speedup 1.0000x reference)
//
#include <hip/hip_runtime.h>

// CurvatureLoss3D — fused 3x3x3 stencil + curvature penalty + zero-crossing
// masked mean, reduced to a scalar.
//
// phi: float32 [2, 1, 192, 192, 192]; out: float32 [1].
// Each output voxel (n, z, y, x) with z,y,x in [0,190) reads the 3x3x3
// neighborhood with corner (z, y, x) (center z+1,y+1,x+1).

constexpr int DIM  = 192;
constexpr int ODIM = 190;          // DIM - 2 (VALID conv)
constexpr long long TOTAL = 2LL * ODIM * ODIM * ODIM;

__global__ __launch_bounds__(256) void curv_main(const float* __restrict__ phi,
                                                 double* __restrict__ acc) {
    const long long stride = (long long)gridDim.x * blockDim.x;
    double sp = 0.0;   // sum(mask * pen)
    double sc = 0.0;   // sum(mask)

    for (long long i = (long long)blockIdx.x * blockDim.x + threadIdx.x;
         i < TOTAL; i += stride) {
        int x = (int)(i % ODIM);
        long long r = i / ODIM;
        int y = (int)(r % ODIM);
        r /= ODIM;
        int z = (int)(r % ODIM);
        int n = (int)(r / ODIM);

        const float* b = phi + (((long long)n * DIM + z) * DIM + y) * DIM + x;

        float p[27];
#pragma unroll
        for (int dz = 0; dz < 3; ++dz)
#pragma unroll
            for (int dy = 0; dy < 3; ++dy)
#pragma unroll
                for (int dx = 0; dx < 3; ++dx)
                    p[(dz * 3 + dy) * 3 + dx] =
                        b[(long long)dz * DIM * DIM + dy * DIM + dx];

#define P(Z, Y, X) p[((Z) * 3 + (Y)) * 3 + (X)]
        const float EPSF = 1e-8f;

        // first derivatives (central diff, vox_width = 1)
        float gx = 0.5f * (P(2, 1, 1) - P(0, 1, 1));   // d/dD
        float gy = 0.5f * (P(1, 2, 1) - P(1, 0, 1));   // d/dH
        float gz = 0.5f * (P(1, 1, 2) - P(1, 1, 0));   // d/dW

        // pure second derivatives
        float c2 = 2.0f * P(1, 1, 1);
        float hxx = P(0, 1, 1) - c2 + P(2, 1, 1);
        float hyy = P(1, 0, 1) - c2 + P(1, 2, 1);
        float hzz = P(1, 1, 0) - c2 + P(1, 1, 2);

        // mixed second derivatives
        float hxy = 0.25f * (P(0, 0, 1) - P(0, 2, 1) - P(2, 0, 1) + P(2, 2, 1));
        float hxz = 0.25f * (P(0, 1, 0) - P(0, 1, 2) - P(2, 1, 0) + P(2, 1, 2));
        float hyz = 0.25f * (P(1, 0, 0) - P(1, 0, 2) - P(1, 2, 0) + P(1, 2, 2));

        float gx2 = gx * gx, gy2 = gy * gy, gz2 = gz * gz;
        float mag2 = gx2 + gy2 + gz2 + EPSF;
        float mag  = sqrtf(mag2);
        float mag3 = mag * mag * mag;

        float cross = gx * gy * hxy + gx * gz * hxz + gy * gz * hyz;
        float inv_mag3 = 1.0f / (mag3 + EPSF);

        float mean_c = (gx2 * (hyy + hzz) + gy2 * (hxx + hzz) + gz2 * (hxx + hyy)
                        - 2.0f * cross) * inv_mag3;

        float lap  = (hxx + hyy + hzz) / (mag + EPSF);
        float quad = (gx2 * hxx + gy2 * hyy + gz2 * hzz + 2.0f * cross) * inv_mag3;
        float gauss = lap - quad;

        float k1 = mean_c + sqrtf(fabsf(mean_c * mean_c - gauss) + EPSF);
        float t  = k1 / (0.5f + EPSF);
        float pen = fmaxf(t * t - 1.0f, 0.0f);

        // zero crossing over the 3x3x3 window
        float mn = p[0], mx = p[0];
#pragma unroll
        for (int k = 1; k < 27; ++k) {
            mn = fminf(mn, p[k]);
            mx = fmaxf(mx, p[k]);
        }
        if (mn * mx < 0.0f) {
            sp += (double)pen;
            sc += 1.0;
        }
#undef P
    }

    // wave-64 reduction
#pragma unroll
    for (int off = 32; off > 0; off >>= 1) {
        sp += __shfl_down(sp, off, 64);
        sc += __shfl_down(sc, off, 64);
    }

    __shared__ double lsp[4], lsc[4];
    int wave = threadIdx.x >> 6;
    int lane = threadIdx.x & 63;
    if (lane == 0) { lsp[wave] = sp; lsc[wave] = sc; }
    __syncthreads();
    if (threadIdx.x == 0) {
        double tp = lsp[0] + lsp[1] + lsp[2] + lsp[3];
        double tc = lsc[0] + lsc[1] + lsc[2] + lsc[3];
        atomicAdd(&acc[0], tp);
        atomicAdd(&acc[1], tc);
    }
}

__global__ void curv_finalize(const double* __restrict__ acc,
                              float* __restrict__ out) {
    out[0] = (float)(acc[0] / (acc[1] + 1e-8));
}

extern "C" void kernel_launch(void* const* d_in, const int* in_sizes, int n_in,
                              void* d_out, int out_size, void* d_ws, size_t ws_size,
                              hipStream_t stream) {
    const float* phi = (const float*)d_in[0];
    float* out = (float*)d_out;
    double* acc = (double*)d_ws;

    hipMemsetAsync(d_ws, 0, 2 * sizeof(double), stream);

    const int block = 256;
    const int grid = (int)((TOTAL + block - 1) / block);
    curv_main<<<grid, block, 0, stream>>>(phi, acc);
    curv_finalize<<<1, 1, 0, stream>>>(acc, out);
}

// Round 2
// 150.456 us; speedup vs baseline: 9.0708x; 9.0708x over previous
//
#include <hip/hip_runtime.h>

// CurvatureLoss3D — 2.5D LDS-tiled fused stencil + curvature penalty +
// zero-crossing masked mean.
//
// phi: float32 [2, 1, 192, 192, 192]; out: float32 [1].
// Block: 256 threads, owns a 32x32 xy output tile, slides over CZ=10 z-planes
// with 3 rotating 34x36 halo planes in LDS. Each thread computes 4 x-adjacent
// voxels per plane (row = tid>>3, x0 = (tid&7)*4), reading its 3x3x6 window
// with float4+float2 LDS reads (row stride 36 keeps 16B alignment provable).

constexpr int DIM  = 192;
constexpr int ODIM = 190;              // valid-conv output extent
constexpr int TX = 32, TY = 32, CZ = 10;
constexpr int NTX = 6, NTY = 6, NTZ = 19;   // 6*32>=190, 19*10=190
constexpr int HX = 34, HY = 34;        // halo extents
constexpr int LX = 36;                 // padded LDS row stride (16B-aligned rows)

__global__ __launch_bounds__(256) void curv_main(const float* __restrict__ phi,
                                                 double* __restrict__ acc) {
    __shared__ __align__(16) float tile[3][HY][LX];

    int bx = blockIdx.x;
    const int tx = bx % NTX; bx /= NTX;
    const int ty = bx % NTY; bx /= NTY;
    const int tz = bx % NTZ; bx /= NTZ;
    const int n  = bx;

    const int xbase = tx * TX, ybase = ty * TY, zbase = tz * CZ;
    const int tid = threadIdx.x;
    const float* pn = phi + (long long)n * DIM * DIM * DIM;

    auto load_plane = [&](int g, int slot) {
        const int gz = zbase + g;                       // always <= 191
        const float* src = pn + (long long)gz * DIM * DIM;
        for (int idx = tid; idx < HY * HX; idx += 256) {
            int ly = idx / HX;
            int lx = idx - ly * HX;
            int iy = ybase + ly; if (iy > DIM - 1) iy = DIM - 1;
            int ix = xbase + lx; if (ix > DIM - 1) ix = DIM - 1;
            tile[slot][ly][lx] = src[iy * DIM + ix];
        }
    };

    load_plane(0, 0);
    load_plane(1, 1);

    const int row = tid >> 3;          // 0..31 (output y within tile)
    const int x0  = (tid & 7) * 4;     // 0..28 (output x within tile, 4 voxels)

    double sp = 0.0, sc = 0.0;
    const float EPSF = 1e-8f;

    for (int zo = 0; zo < CZ; ++zo) {
        load_plane(zo + 2, (zo + 2) % 3);
        __syncthreads();

        const int ps[3] = { zo % 3, (zo + 1) % 3, (zo + 2) % 3 };

        // 3(z) x 3(y) x 6(x) register window
        float v[3][3][6];
#pragma unroll
        for (int dz = 0; dz < 3; ++dz) {
#pragma unroll
            for (int dy = 0; dy < 3; ++dy) {
                const float* rp = &tile[ps[dz]][row + dy][x0];
                const float4 a = *(const float4*)rp;
                const float2 b = *(const float2*)(rp + 4);
                v[dz][dy][0] = a.x; v[dz][dy][1] = a.y;
                v[dz][dy][2] = a.z; v[dz][dy][3] = a.w;
                v[dz][dy][4] = b.x; v[dz][dy][5] = b.y;
            }
        }

        // per-column min/max over the 9 (z,y) values
        float cmn[6], cmx[6];
#pragma unroll
        for (int c = 0; c < 6; ++c) {
            float mn = v[0][0][c], mx = v[0][0][c];
#pragma unroll
            for (int zz = 0; zz < 3; ++zz)
#pragma unroll
                for (int yy = 0; yy < 3; ++yy) {
                    mn = fminf(mn, v[zz][yy][c]);
                    mx = fmaxf(mx, v[zz][yy][c]);
                }
            cmn[c] = mn; cmx[c] = mx;
        }

        const int oy = ybase + row;
        const bool vy = (oy < ODIM);

#pragma unroll
        for (int j = 0; j < 4; ++j) {
            const int ox = xbase + x0 + j;
            const bool valid = vy && (ox < ODIM);

#define P(Z, Y, X) v[Z][Y][j + (X)]
            // first derivatives (z = dim0, y = dim1, x = dim2 of the volume)
            float gx = 0.5f * (P(2, 1, 1) - P(0, 1, 1));
            float gy = 0.5f * (P(1, 2, 1) - P(1, 0, 1));
            float gz = 0.5f * (P(1, 1, 2) - P(1, 1, 0));

            float c2  = 2.0f * P(1, 1, 1);
            float hxx = P(0, 1, 1) - c2 + P(2, 1, 1);
            float hyy = P(1, 0, 1) - c2 + P(1, 2, 1);
            float hzz = P(1, 1, 0) - c2 + P(1, 1, 2);

            float hxy = 0.25f * (P(0, 0, 1) - P(0, 2, 1) - P(2, 0, 1) + P(2, 2, 1));
            float hxz = 0.25f * (P(0, 1, 0) - P(0, 1, 2) - P(2, 1, 0) + P(2, 1, 2));
            float hyz = 0.25f * (P(1, 0, 0) - P(1, 0, 2) - P(1, 2, 0) + P(1, 2, 2));
#undef P

            float gx2 = gx * gx, gy2 = gy * gy, gz2 = gz * gz;
            float mag2 = gx2 + gy2 + gz2 + EPSF;
            float mag  = sqrtf(mag2);
            float mag3 = mag * mag * mag;

            float cross = gx * gy * hxy + gx * gz * hxz + gy * gz * hyz;
            float inv_mag3 = __builtin_amdgcn_rcpf(mag3 + EPSF);
            float inv_mag  = __builtin_amdgcn_rcpf(mag  + EPSF);

            float mean_c = (gx2 * (hyy + hzz) + gy2 * (hxx + hzz) +
                            gz2 * (hxx + hyy) - 2.0f * cross) * inv_mag3;
            float lap  = (hxx + hyy + hzz) * inv_mag;
            float quad = (gx2 * hxx + gy2 * hyy + gz2 * hzz + 2.0f * cross) * inv_mag3;
            float gauss = lap - quad;

            float k1 = mean_c + sqrtf(fabsf(mean_c * mean_c - gauss) + EPSF);
            float t  = k1 * 2.0f;   // k1 / (0.5 + 1e-8); 0.5+1e-8 == 0.5 in f32
            float pen = fmaxf(t * t - 1.0f, 0.0f);

            float mn = fminf(fminf(cmn[j], cmn[j + 1]), cmn[j + 2]);
            float mx = fmaxf(fmaxf(cmx[j], cmx[j + 1]), cmx[j + 2]);

            if (valid && (mn * mx < 0.0f)) {
                sp += (double)pen;
                sc += 1.0;
            }
        }
        __syncthreads();
    }

    // wave-64 reduction
#pragma unroll
    for (int off = 32; off > 0; off >>= 1) {
        sp += __shfl_down(sp, off, 64);
        sc += __shfl_down(sc, off, 64);
    }

    __shared__ double lsp[4], lsc[4];
    const int wave = tid >> 6, lane = tid & 63;
    if (lane == 0) { lsp[wave] = sp; lsc[wave] = sc; }
    __syncthreads();
    if (tid == 0) {
        atomicAdd(&acc[0], lsp[0] + lsp[1] + lsp[2] + lsp[3]);
        atomicAdd(&acc[1], lsc[0] + lsc[1] + lsc[2] + lsc[3]);
    }
}

__global__ void curv_finalize(const double* __restrict__ acc,
                              float* __restrict__ out) {
    out[0] = (float)(acc[0] / (acc[1] + 1e-8));
}

extern "C" void kernel_launch(void* const* d_in, const int* in_sizes, int n_in,
                              void* d_out, int out_size, void* d_ws, size_t ws_size,
                              hipStream_t stream) {
    const float* phi = (const float*)d_in[0];
    float* out = (float*)d_out;
    double* acc = (double*)d_ws;

    hipMemsetAsync(d_ws, 0, 2 * sizeof(double), stream);

    const int grid = 2 * NTZ * NTY * NTX;   // 1368 blocks
    curv_main<<<grid, 256, 0, stream>>>(phi, acc);
    curv_finalize<<<1, 1, 0, stream>>>(acc, out);
}